// Round 1
// baseline (414.784 us; speedup 1.0000x reference)
//
#include <hip/hip_runtime.h>
#include <math.h>

// Problem constants (fixed by the reference: [16,3,1024,1024] fp32 inputs)
#define NP      8
#define NBINS   256
#define BC      48
#define HH      1024
#define WW      1024
#define RPB     32                  // rows per block (32 | 128 -> one h-patch per block)
#define THREADS 256
#define NBLK1   1536                // BC*HH / RPB  (exactly 6 blocks/CU)
#define BLK_PER_I 192               // NBLK1 / NP   (blocks sharing one h-patch index)
#define PD      8                   // prefetch pipeline depth (row-units in flight)
#define PATCH_ELEMS (BC * 128 * 128)
#define N_TOTAL ((long long)BC * HH * WW)

// ---- workspace layout (Path A: per-block hist dump, no global atomics) ----
#define GH_BYTES   ((size_t)NBLK1 * 2048 * 2)          // u16 hist per block: 6.29 MB
#define GS_OFF     GH_BYTES
#define GS_BYTES   ((size_t)NBLK1 * NP * 4)            // per-block 8 j-sums: 48 KB
#define ENT_OFF    (GS_OFF + GS_BYTES)                 // 8-byte aligned
#define ENT_BYTES  (64 * 8)
#define GT_OFF     (ENT_OFF + ENT_BYTES)
#define PATHA_BYTES (GT_OFF + 64 * 4)
// ---- Path B (fallback, tiny ws): atomic flush ----
#define B_GHIST_BYTES (64 * NBINS * 4)                 // 64 KB
#define B_GSUM_OFF    B_GHIST_BYTES
#define B_ENT_OFF     (B_GSUM_OFF + 256)               // 8-aligned

__device__ __forceinline__ void proc1(const float4 s, const float4 h,
                                      float& acc, unsigned int* histj)
{
    acc += fabsf(s.x - h.x);
    acc += fabsf(s.y - h.y);
    acc += fabsf(s.z - h.z);
    acc += fabsf(s.w - h.w);
    int b0 = min(max((int)(h.x * 255.0f), 0), 255);
    int b1 = min(max((int)(h.y * 255.0f), 0), 255);
    int b2 = min(max((int)(h.z * 255.0f), 0), 255);
    int b3 = min(max((int)(h.w * 255.0f), 0), 255);
    atomicAdd(&histj[b0], 1u);
    atomicAdd(&histj[b1], 1u);
    atomicAdd(&histj[b2], 1u);
    atomicAdd(&histj[b3], 1u);
}

// Pass 1: per-patch histogram + per-patch sum |sr-hr|, depth-PD static pipeline.
// ATOMIC=false: dump packed-u16 per-block hist (gh32) + plain per-block j-sums (gs)
// ATOMIC=true : global atomicAdd into 64x256 u32 hist + 64 f32 sums
template <bool ATOMIC>
__global__ __launch_bounds__(THREADS, 4)     // 4 waves/EU -> VGPR cap 128: room for the pipeline
void entrop_pass1(const float* __restrict__ sr, const float* __restrict__ hr,
                  unsigned int* __restrict__ gh32, float* __restrict__ gs)
{
    __shared__ unsigned int hist[NP * NBINS];
    const int t  = threadIdx.x;
    const int r0 = blockIdx.x * RPB;

    const float4* s4 = (const float4*)sr + (size_t)r0 * (WW / 4) + t;
    const float4* h4 = (const float4*)hr + (size_t)r0 * (WW / 4) + t;

    // Issue the deep prefetch FIRST so HBM latency hides under LDS init + barrier.
    float4 sb[PD], hb[PD];
#pragma unroll
    for (int k = 0; k < PD; ++k) {
        sb[k] = s4[k * (WW / 4)];
        hb[k] = h4[k * (WW / 4)];
    }

#pragma unroll
    for (int m = t; m < NP * NBINS; m += THREADS) hist[m] = 0;
    __syncthreads();

    const int i = (r0 & (HH - 1)) >> 7;     // h-patch (block-uniform)
    const int j = t >> 5;                   // w-patch for this thread
    unsigned int* histj = &hist[j << 8];

    float acc = 0.0f;
    // Steady state: ~2*(PD-1)+2 wave-loads (~15 KB/wave) in flight.
    // All register-array indices are compile-time constants (inner loop fully
    // unrolled, outer loop kept rolled) -> no scratch.
#pragma unroll 1
    for (int grp = 0; grp < RPB / PD - 1; ++grp) {
        const float4* sn = s4 + (size_t)(grp + 1) * PD * (WW / 4);
        const float4* hn = h4 + (size_t)(grp + 1) * PD * (WW / 4);
#pragma unroll
        for (int k = 0; k < PD; ++k) {
            float4 s = sb[k], h = hb[k];
            sb[k] = sn[k * (WW / 4)];
            hb[k] = hn[k * (WW / 4)];
            proc1(s, h, acc, histj);
        }
    }
#pragma unroll
    for (int k = 0; k < PD; ++k) proc1(sb[k], hb[k], acc, histj);

    // reduce |d| within each 32-lane group (all lanes share j)
    for (int off = 16; off; off >>= 1) acc += __shfl_down(acc, off, 32);
    if ((t & 31) == 0) {
        if (ATOMIC) atomicAdd(&gs[i * NP + j], acc);
        else        gs[blockIdx.x * NP + j] = acc;
    }

    __syncthreads();
    if (ATOMIC) {
        for (int m = t; m < NP * NBINS; m += THREADS) {
            unsigned int c = hist[m];
            if (c) atomicAdd(&gh32[i * NP * NBINS + m], c);
        }
    } else {
        // pack 2 bins per u32 (counts <= RPB*128 = 4096 per block-bin), coalesced
#pragma unroll
        for (int m = t; m < NP * NBINS / 2; m += THREADS)
            gh32[(size_t)blockIdx.x * (NP * NBINS / 2) + m] =
                hist[2 * m] | (hist[2 * m + 1] << 16);
    }
}

// Path A reduce: 64 blocks, one per patch p=(i,j). Sums 192 per-block u16
// hists -> counts -> fp64 entropy; sums 192 per-block j-sums -> gsumT.
// Blocks sharing h-patch i: b = 32*u + 4*i + e, u in [0,48), e in [0,4).
__global__ __launch_bounds__(THREADS)
void entrop_reduceA(const unsigned short* __restrict__ gh,
                    const float* __restrict__ gs,
                    double* __restrict__ ent, float* __restrict__ gsumT)
{
    const int p = blockIdx.x, i = p >> 3, jj = p & 7;
    const int t = threadIdx.x;

    unsigned int cnt = 0;
    const unsigned short* col = gh + jj * NBINS + t;
#pragma unroll 1
    for (int u = 0; u < 48; u += 2) {            // 8 independent loads per iter
#pragma unroll
        for (int v = 0; v < 2; ++v)
#pragma unroll
            for (int e = 0; e < 4; ++e)
                cnt += col[(size_t)(32 * (u + v) + 4 * i + e) * 2048];
    }
    double term = 0.0;
    if (cnt) {
        double pd = (double)cnt * (1.0 / (double)PATCH_ELEMS);
        term = pd * log2(pd);
    }

    float sg = 0.0f;
    if (t < BLK_PER_I) {                         // 192 < 256: one load per thread
        int u = t >> 2, e = t & 3;
        sg = gs[(size_t)(32 * u + 4 * i + e) * NP + jj];
    }

    for (int off = 32; off; off >>= 1) {
        term += __shfl_down(term, off, 64);
        sg   += __shfl_down(sg, off, 64);
    }
    __shared__ double rd[4];
    __shared__ float  rf[4];
    if ((t & 63) == 0) { rd[t >> 6] = term; rf[t >> 6] = sg; }
    __syncthreads();
    if (t == 0) {
        ent[p]   = -(rd[0] + rd[1] + rd[2] + rd[3]);
        gsumT[p] = rf[0] + rf[1] + rf[2] + rf[3];
    }
}

// Path B reduce: entropy from the atomically-accumulated u32 hist.
__global__ __launch_bounds__(THREADS)
void entrop_reduceB(const unsigned int* __restrict__ ghist, double* __restrict__ ent)
{
    const int p = blockIdx.x, t = threadIdx.x;
    unsigned int c = ghist[p * NBINS + t];
    double term = 0.0;
    if (c) {
        double pd = (double)c * (1.0 / (double)PATCH_ELEMS);
        term = pd * log2(pd);
    }
    for (int off = 32; off; off >>= 1) term += __shfl_down(term, off, 64);
    __shared__ double rd[4];
    if ((t & 63) == 0) rd[t >> 6] = term;
    __syncthreads();
    if (t == 0) ent[p] = -(rd[0] + rd[1] + rd[2] + rd[3]);
}

// Final: 1 wave. min/max over 64 entropies, weighted sum, scalar out.
__global__ void entrop_final(const double* __restrict__ ent,
                             const float* __restrict__ gsumT,
                             float* __restrict__ out)
{
    const int t = threadIdx.x;   // 64 threads
    double e = ent[t];
    double mn = e, mx = e;
#pragma unroll
    for (int off = 32; off; off >>= 1) {
        mn = fmin(mn, __shfl_xor(mn, off, 64));
        mx = fmax(mx, __shfl_xor(mx, off, 64));
    }
    double contrib = (e - mn) / mx * (double)gsumT[t];
#pragma unroll
    for (int off = 32; off; off >>= 1) contrib += __shfl_xor(contrib, off, 64);
    if (t == 0) out[0] = (float)(contrib / (double)N_TOTAL);
}

extern "C" void kernel_launch(void* const* d_in, const int* in_sizes, int n_in,
                              void* d_out, int out_size, void* d_ws, size_t ws_size,
                              hipStream_t stream)
{
    const float* sr = (const float*)d_in[0];
    const float* hr = (const float*)d_in[1];
    float* out = (float*)d_out;
    char* ws = (char*)d_ws;

    if (ws_size >= PATHA_BYTES) {
        unsigned int*   gh32  = (unsigned int*)ws;                 // u16 hists, u32-packed
        float*          gs    = (float*)(ws + GS_OFF);
        double*         ent   = (double*)(ws + ENT_OFF);
        float*          gsumT = (float*)(ws + GT_OFF);
        // everything fully overwritten before read -> no memset needed
        entrop_pass1<false><<<NBLK1, THREADS, 0, stream>>>(sr, hr, gh32, gs);
        entrop_reduceA<<<64, THREADS, 0, stream>>>((const unsigned short*)gh32, gs, ent, gsumT);
        entrop_final<<<1, 64, 0, stream>>>(ent, gsumT, out);
    } else {
        unsigned int* ghist = (unsigned int*)ws;
        float*        gsum  = (float*)(ws + B_GSUM_OFF);
        double*       ent   = (double*)(ws + B_ENT_OFF);
        hipMemsetAsync(ws, 0, B_GSUM_OFF + 256, stream);
        entrop_pass1<true><<<NBLK1, THREADS, 0, stream>>>(sr, hr, ghist, gsum);
        entrop_reduceB<<<64, THREADS, 0, stream>>>(ghist, ent);
        entrop_final<<<1, 64, 0, stream>>>(ent, gsum, out);
    }
}

// Round 2
// 409.739 us; speedup vs baseline: 1.0123x; 1.0123x over previous
//
#include <hip/hip_runtime.h>
#include <math.h>

// Problem constants (fixed by the reference: [16,3,1024,1024] fp32 inputs)
#define NP      8
#define NBINS   256
#define BC      48
#define HH      1024
#define WW      1024
#define RPB     64                  // rows per block (64 | 128 -> one h-patch per block)
#define THREADS 256
#define NBLK1   768                 // BC*HH / RPB  (exactly 3 blocks/CU, no tail)
#define BLK_PER_I 96                // NBLK1 / NP   (blocks sharing one h-patch index)
#define PD      8                   // prefetch pipeline depth (row-units in flight)
#define PATCH_ELEMS (BC * 128 * 128)
#define N_TOTAL ((long long)BC * HH * WW)

// ---- workspace layout (Path A: per-block hist dump, no global atomics) ----
#define GH_BYTES   ((size_t)NBLK1 * 2048 * 2)          // u16 hist per block: 3.15 MB
#define GS_OFF     GH_BYTES
#define GS_BYTES   ((size_t)NBLK1 * NP * 4)            // per-block 8 j-sums: 24.6 KB
#define ENT_OFF    (GS_OFF + GS_BYTES)                 // 8-byte aligned
#define ENT_BYTES  (64 * 8)
#define GT_OFF     (ENT_OFF + ENT_BYTES)
#define PATHA_BYTES (GT_OFF + 64 * 4)
// ---- Path B (fallback, tiny ws): atomic flush ----
#define B_GHIST_BYTES (64 * NBINS * 4)                 // 64 KB
#define B_GSUM_OFF    B_GHIST_BYTES
#define B_ENT_OFF     (B_GSUM_OFF + 256)               // 8-aligned

__device__ __forceinline__ void proc1(const float4 s, const float4 h,
                                      float& acc, unsigned int* histj)
{
    acc += fabsf(s.x - h.x);
    acc += fabsf(s.y - h.y);
    acc += fabsf(s.z - h.z);
    acc += fabsf(s.w - h.w);
    int b0 = min(max((int)(h.x * 255.0f), 0), 255);
    int b1 = min(max((int)(h.y * 255.0f), 0), 255);
    int b2 = min(max((int)(h.z * 255.0f), 0), 255);
    int b3 = min(max((int)(h.w * 255.0f), 0), 255);
    atomicAdd(&histj[b0], 1u);
    atomicAdd(&histj[b1], 1u);
    atomicAdd(&histj[b2], 1u);
    atomicAdd(&histj[b3], 1u);
}

// Pass 1: per-patch histogram + per-patch sum |sr-hr|, depth-PD static pipeline.
// amdgpu_waves_per_eu(4,4) pins the allocator to a 128-VGPR budget (512/4):
// round-1 evidence showed __launch_bounds__(256,4) alone lets the backend
// re-target 8 waves/EU (64 VGPR) and spill the pipeline (+75 MB scratch writes).
// ATOMIC=false: dump packed-u16 per-block hist (gh32) + plain per-block j-sums (gs)
// ATOMIC=true : global atomicAdd into 64x256 u32 hist + 64 f32 sums
template <bool ATOMIC>
__global__ __launch_bounds__(THREADS)
__attribute__((amdgpu_waves_per_eu(4, 4)))
void entrop_pass1(const float* __restrict__ sr, const float* __restrict__ hr,
                  unsigned int* __restrict__ gh32, float* __restrict__ gs)
{
    __shared__ unsigned int hist[NP * NBINS];
    const int t  = threadIdx.x;
    const int r0 = blockIdx.x * RPB;

    const float4* s4 = (const float4*)sr + (size_t)r0 * (WW / 4) + t;
    const float4* h4 = (const float4*)hr + (size_t)r0 * (WW / 4) + t;

    // Issue the deep prefetch FIRST so HBM latency hides under LDS init + barrier.
    float4 sb[PD], hb[PD];
#pragma unroll
    for (int k = 0; k < PD; ++k) {
        sb[k] = s4[k * (WW / 4)];
        hb[k] = h4[k * (WW / 4)];
    }

#pragma unroll
    for (int m = t; m < NP * NBINS; m += THREADS) hist[m] = 0;
    __syncthreads();

    const int i = (r0 & (HH - 1)) >> 7;     // h-patch (block-uniform; 64 | 128)
    const int j = t >> 5;                   // w-patch for this thread
    unsigned int* histj = &hist[j << 8];

    float acc = 0.0f;
    // Steady state: 2*PD loads (~16 KB/wave) in flight. All register-array
    // indices are compile-time constants (inner loop fully unrolled, outer
    // loop kept rolled) -> no scratch, given the 128-VGPR budget.
#pragma unroll 1
    for (int grp = 0; grp < RPB / PD - 1; ++grp) {
        const float4* sn = s4 + (size_t)(grp + 1) * PD * (WW / 4);
        const float4* hn = h4 + (size_t)(grp + 1) * PD * (WW / 4);
#pragma unroll
        for (int k = 0; k < PD; ++k) {
            float4 s = sb[k], h = hb[k];
            sb[k] = sn[k * (WW / 4)];
            hb[k] = hn[k * (WW / 4)];
            proc1(s, h, acc, histj);
        }
    }
#pragma unroll
    for (int k = 0; k < PD; ++k) proc1(sb[k], hb[k], acc, histj);

    // reduce |d| within each 32-lane group (all lanes share j)
    for (int off = 16; off; off >>= 1) acc += __shfl_down(acc, off, 32);
    if ((t & 31) == 0) {
        if (ATOMIC) atomicAdd(&gs[i * NP + j], acc);
        else        gs[blockIdx.x * NP + j] = acc;
    }

    __syncthreads();
    if (ATOMIC) {
        for (int m = t; m < NP * NBINS; m += THREADS) {
            unsigned int c = hist[m];
            if (c) atomicAdd(&gh32[i * NP * NBINS + m], c);
        }
    } else {
        // pack 2 bins per u32 (counts <= RPB*128 = 8192 per block-bin), coalesced
#pragma unroll
        for (int m = t; m < NP * NBINS / 2; m += THREADS)
            gh32[(size_t)blockIdx.x * (NP * NBINS / 2) + m] =
                hist[2 * m] | (hist[2 * m + 1] << 16);
    }
}

// Path A reduce: 64 blocks, one per patch p=(i,jj). Sums 96 per-block u16
// hists -> counts -> fp64 entropy; sums 96 per-block j-sums -> gsumT.
// Blocks sharing h-patch i (RPB=64): b = 16*u + 2*i + e, u in [0,48), e in [0,2).
__global__ __launch_bounds__(THREADS)
void entrop_reduceA(const unsigned short* __restrict__ gh,
                    const float* __restrict__ gs,
                    double* __restrict__ ent, float* __restrict__ gsumT)
{
    const int p = blockIdx.x, i = p >> 3, jj = p & 7;
    const int t = threadIdx.x;

    unsigned int cnt = 0;
    const unsigned short* col = gh + jj * NBINS + t;
#pragma unroll 1
    for (int u = 0; u < 48; u += 4) {            // 8 independent loads per iter
#pragma unroll
        for (int v = 0; v < 4; ++v)
#pragma unroll
            for (int e = 0; e < 2; ++e)
                cnt += col[(size_t)(16 * (u + v) + 2 * i + e) * 2048];
    }
    double term = 0.0;
    if (cnt) {
        double pd = (double)cnt * (1.0 / (double)PATCH_ELEMS);
        term = pd * log2(pd);
    }

    float sg = 0.0f;
    if (t < BLK_PER_I) {                         // 96 < 256: one load per thread
        int u = t >> 1, e = t & 1;
        sg = gs[(size_t)(16 * u + 2 * i + e) * NP + jj];
    }

    for (int off = 32; off; off >>= 1) {
        term += __shfl_down(term, off, 64);
        sg   += __shfl_down(sg, off, 64);
    }
    __shared__ double rd[4];
    __shared__ float  rf[4];
    if ((t & 63) == 0) { rd[t >> 6] = term; rf[t >> 6] = sg; }
    __syncthreads();
    if (t == 0) {
        ent[p]   = -(rd[0] + rd[1] + rd[2] + rd[3]);
        gsumT[p] = rf[0] + rf[1] + rf[2] + rf[3];
    }
}

// Path B reduce: entropy from the atomically-accumulated u32 hist.
__global__ __launch_bounds__(THREADS)
void entrop_reduceB(const unsigned int* __restrict__ ghist, double* __restrict__ ent)
{
    const int p = blockIdx.x, t = threadIdx.x;
    unsigned int c = ghist[p * NBINS + t];
    double term = 0.0;
    if (c) {
        double pd = (double)c * (1.0 / (double)PATCH_ELEMS);
        term = pd * log2(pd);
    }
    for (int off = 32; off; off >>= 1) term += __shfl_down(term, off, 64);
    __shared__ double rd[4];
    if ((t & 63) == 0) rd[t >> 6] = term;
    __syncthreads();
    if (t == 0) ent[p] = -(rd[0] + rd[1] + rd[2] + rd[3]);
}

// Final: 1 wave. min/max over 64 entropies, weighted sum, scalar out.
__global__ void entrop_final(const double* __restrict__ ent,
                             const float* __restrict__ gsumT,
                             float* __restrict__ out)
{
    const int t = threadIdx.x;   // 64 threads
    double e = ent[t];
    double mn = e, mx = e;
#pragma unroll
    for (int off = 32; off; off >>= 1) {
        mn = fmin(mn, __shfl_xor(mn, off, 64));
        mx = fmax(mx, __shfl_xor(mx, off, 64));
    }
    double contrib = (e - mn) / mx * (double)gsumT[t];
#pragma unroll
    for (int off = 32; off; off >>= 1) contrib += __shfl_xor(contrib, off, 64);
    if (t == 0) out[0] = (float)(contrib / (double)N_TOTAL);
}

extern "C" void kernel_launch(void* const* d_in, const int* in_sizes, int n_in,
                              void* d_out, int out_size, void* d_ws, size_t ws_size,
                              hipStream_t stream)
{
    const float* sr = (const float*)d_in[0];
    const float* hr = (const float*)d_in[1];
    float* out = (float*)d_out;
    char* ws = (char*)d_ws;

    if (ws_size >= PATHA_BYTES) {
        unsigned int*   gh32  = (unsigned int*)ws;                 // u16 hists, u32-packed
        float*          gs    = (float*)(ws + GS_OFF);
        double*         ent   = (double*)(ws + ENT_OFF);
        float*          gsumT = (float*)(ws + GT_OFF);
        // everything fully overwritten before read -> no memset needed
        entrop_pass1<false><<<NBLK1, THREADS, 0, stream>>>(sr, hr, gh32, gs);
        entrop_reduceA<<<64, THREADS, 0, stream>>>((const unsigned short*)gh32, gs, ent, gsumT);
        entrop_final<<<1, 64, 0, stream>>>(ent, gsumT, out);
    } else {
        unsigned int* ghist = (unsigned int*)ws;
        float*        gsum  = (float*)(ws + B_GSUM_OFF);
        double*       ent   = (double*)(ws + B_ENT_OFF);
        hipMemsetAsync(ws, 0, B_GSUM_OFF + 256, stream);
        entrop_pass1<true><<<NBLK1, THREADS, 0, stream>>>(sr, hr, ghist, gsum);
        entrop_reduceB<<<64, THREADS, 0, stream>>>(ghist, ent);
        entrop_final<<<1, 64, 0, stream>>>(ent, gsum, out);
    }
}

// Round 3
// 381.061 us; speedup vs baseline: 1.0885x; 1.0753x over previous
//
#include <hip/hip_runtime.h>
#include <math.h>

// Problem constants (fixed by the reference: [16,3,1024,1024] fp32 inputs)
#define NP      8
#define NBINS   256
#define BC      48
#define HH      1024
#define WW      1024
#define RPB     16                  // rows per block (16 | 128 -> one h-patch per block)
#define THREADS 256
#define NBLK1   3072                // BC*HH / RPB
#define BLK_PER_I 384               // NBLK1 / NP  (blocks sharing one h-patch index)
#define PATCH_ELEMS (BC * 128 * 128)
#define N_TOTAL ((long long)BC * HH * WW)

// ---- workspace layout (Path A: per-block hist dump, no global atomics) ----
#define GH_BYTES   ((size_t)NBLK1 * 2048 * 2)          // u16 hist per block: 12.58 MB
#define GS_OFF     GH_BYTES
#define GS_BYTES   ((size_t)NBLK1 * NP * 4)            // per-block 8 j-sums: 98 KB
#define ENT_OFF    (GS_OFF + GS_BYTES)                 // 8-byte aligned
#define ENT_BYTES  (64 * 8)
#define GT_OFF     (ENT_OFF + ENT_BYTES)
#define PATHA_BYTES (GT_OFF + 64 * 4)
// ---- Path B (fallback, tiny ws): atomic flush ----
#define B_GHIST_BYTES (64 * NBINS * 4)                 // 64 KB
#define B_GSUM_OFF    B_GHIST_BYTES
#define B_ENT_OFF     (B_GSUM_OFF + 256)               // 8-aligned

typedef float f4 __attribute__((ext_vector_type(4)));

// Non-temporal loads: sr/hr are single-touch streams; nt skips L1 allocation
// (round-2 evidence: read path pinned at ~5 B/cy/CU with every other pipe idle
// across occupancy 31-72% -> suspected L1/TCP allocation/miss-tracking limit).
__device__ __forceinline__ void load_g(const f4* __restrict__ s4,
                                       const f4* __restrict__ h4,
                                       int g, f4* sb, f4* hb)
{
#pragma unroll
    for (int k = 0; k < 2; ++k) {
        sb[k] = __builtin_nontemporal_load(&s4[(g * 2 + k) * (WW / 4)]);
        hb[k] = __builtin_nontemporal_load(&h4[(g * 2 + k) * (WW / 4)]);
    }
}

__device__ __forceinline__ void proc_g(const f4* sb, const f4* hb,
                                       float& acc, unsigned int* histj)
{
#pragma unroll
    for (int k = 0; k < 2; ++k) {
        f4 s = sb[k], h = hb[k];
#pragma unroll
        for (int e = 0; e < 4; ++e) {
            acc += fabsf(s[e] - h[e]);
            int b = min(max((int)(h[e] * 255.0f), 0), 255);
            atomicAdd(&histj[b], 1u);
        }
    }
}

// Pass 1: per-patch histogram + per-patch sum |sr-hr|.
// ATOMIC=false: dump packed-u16 per-block hist (gh32) + plain per-block j-sums (gs)
// ATOMIC=true : global atomicAdd into 64x256 u32 hist + 64 f32 sums
template <bool ATOMIC>
__global__ __launch_bounds__(THREADS, 8)
void entrop_pass1(const float* __restrict__ sr, const float* __restrict__ hr,
                  unsigned int* __restrict__ gh32, float* __restrict__ gs)
{
    __shared__ unsigned int hist[NP * NBINS];
    const int t = threadIdx.x;
#pragma unroll
    for (int m = t; m < NP * NBINS; m += THREADS) hist[m] = 0;
    __syncthreads();

    const int r0 = blockIdx.x * RPB;
    const int i  = (r0 & (HH - 1)) >> 7;    // h-patch (block-uniform)
    const int j  = t >> 5;                  // w-patch for this thread
    unsigned int* histj = &hist[j << 8];

    const f4* s4 = (const f4*)sr + (size_t)r0 * (WW / 4) + t;
    const f4* h4 = (const f4*)hr + (size_t)r0 * (WW / 4) + t;

    float acc = 0.0f;
    f4 sA[2], hA[2], sB[2], hB[2];
    load_g(s4, h4, 0, sA, hA);
#pragma unroll
    for (int g = 0; g < 7; ++g) {
        if (g & 1) { load_g(s4, h4, g + 1, sA, hA); proc_g(sB, hB, acc, histj); }
        else       { load_g(s4, h4, g + 1, sB, hB); proc_g(sA, hA, acc, histj); }
    }
    proc_g(sB, hB, acc, histj);

    // reduce |d| within each 32-lane group (all lanes share j)
    for (int off = 16; off; off >>= 1) acc += __shfl_down(acc, off, 32);
    if ((t & 31) == 0) {
        if (ATOMIC) atomicAdd(&gs[i * NP + j], acc);
        else        gs[blockIdx.x * NP + j] = acc;
    }

    __syncthreads();
    if (ATOMIC) {
        for (int m = t; m < NP * NBINS; m += THREADS) {
            unsigned int c = hist[m];
            if (c) atomicAdd(&gh32[i * NP * NBINS + m], c);
        }
    } else {
        // pack 2 bins per u32 (counts < 2048 per block-bin), coalesced stores
#pragma unroll
        for (int m = t; m < NP * NBINS / 2; m += THREADS)
            gh32[(size_t)blockIdx.x * (NP * NBINS / 2) + m] =
                hist[2 * m] | (hist[2 * m + 1] << 16);
    }
}

// Path A reduce: 64 blocks, one per patch p=(i,j). Sums 384 per-block u16
// hists -> counts -> fp64 entropy; sums 384 per-block j-sums -> gsumT.
__global__ __launch_bounds__(THREADS)
void entrop_reduceA(const unsigned short* __restrict__ gh,
                    const float* __restrict__ gs,
                    double* __restrict__ ent, float* __restrict__ gsumT)
{
    const int p = blockIdx.x, i = p >> 3, jj = p & 7;
    const int t = threadIdx.x;

    unsigned int cnt = 0;
    const unsigned short* col = gh + jj * NBINS + t;
    for (int g = 0; g < BLK_PER_I / 8; ++g) {
#pragma unroll
        for (int d = 0; d < 8; ++d)
            cnt += col[(size_t)(64 * g + 8 * i + d) * 2048];
    }
    double term = 0.0;
    if (cnt) {
        double pd = (double)cnt * (1.0 / (double)PATCH_ELEMS);
        term = pd * log2(pd);
    }
    float sg = 0.0f;
    for (int idx = t; idx < BLK_PER_I; idx += THREADS) {
        int g = idx >> 3, d = idx & 7;
        sg += gs[(size_t)(64 * g + 8 * i + d) * NP + jj];
    }

    for (int off = 32; off; off >>= 1) {
        term += __shfl_down(term, off, 64);
        sg   += __shfl_down(sg, off, 64);
    }
    __shared__ double rd[4];
    __shared__ float  rf[4];
    if ((t & 63) == 0) { rd[t >> 6] = term; rf[t >> 6] = sg; }
    __syncthreads();
    if (t == 0) {
        ent[p]   = -(rd[0] + rd[1] + rd[2] + rd[3]);
        gsumT[p] = rf[0] + rf[1] + rf[2] + rf[3];
    }
}

// Path B reduce: entropy from the atomically-accumulated u32 hist.
__global__ __launch_bounds__(THREADS)
void entrop_reduceB(const unsigned int* __restrict__ ghist, double* __restrict__ ent)
{
    const int p = blockIdx.x, t = threadIdx.x;
    unsigned int c = ghist[p * NBINS + t];
    double term = 0.0;
    if (c) {
        double pd = (double)c * (1.0 / (double)PATCH_ELEMS);
        term = pd * log2(pd);
    }
    for (int off = 32; off; off >>= 1) term += __shfl_down(term, off, 64);
    __shared__ double rd[4];
    if ((t & 63) == 0) rd[t >> 6] = term;
    __syncthreads();
    if (t == 0) ent[p] = -(rd[0] + rd[1] + rd[2] + rd[3]);
}

// Final: 1 wave. min/max over 64 entropies, weighted sum, scalar out.
__global__ void entrop_final(const double* __restrict__ ent,
                             const float* __restrict__ gsumT,
                             float* __restrict__ out)
{
    const int t = threadIdx.x;   // 64 threads
    double e = ent[t];
    double mn = e, mx = e;
#pragma unroll
    for (int off = 32; off; off >>= 1) {
        mn = fmin(mn, __shfl_xor(mn, off, 64));
        mx = fmax(mx, __shfl_xor(mx, off, 64));
    }
    double contrib = (e - mn) / mx * (double)gsumT[t];
#pragma unroll
    for (int off = 32; off; off >>= 1) contrib += __shfl_xor(contrib, off, 64);
    if (t == 0) out[0] = (float)(contrib / (double)N_TOTAL);
}

extern "C" void kernel_launch(void* const* d_in, const int* in_sizes, int n_in,
                              void* d_out, int out_size, void* d_ws, size_t ws_size,
                              hipStream_t stream)
{
    const float* sr = (const float*)d_in[0];
    const float* hr = (const float*)d_in[1];
    float* out = (float*)d_out;
    char* ws = (char*)d_ws;

    if (ws_size >= PATHA_BYTES) {
        unsigned int*   gh32  = (unsigned int*)ws;                 // u16 hists, u32-packed
        float*          gs    = (float*)(ws + GS_OFF);
        double*         ent   = (double*)(ws + ENT_OFF);
        float*          gsumT = (float*)(ws + GT_OFF);
        // everything fully overwritten before read -> no memset needed
        entrop_pass1<false><<<NBLK1, THREADS, 0, stream>>>(sr, hr, gh32, gs);
        entrop_reduceA<<<64, THREADS, 0, stream>>>((const unsigned short*)gh32, gs, ent, gsumT);
        entrop_final<<<1, 64, 0, stream>>>(ent, gsumT, out);
    } else {
        unsigned int* ghist = (unsigned int*)ws;
        float*        gsum  = (float*)(ws + B_GSUM_OFF);
        double*       ent   = (double*)(ws + B_ENT_OFF);
        hipMemsetAsync(ws, 0, B_GSUM_OFF + 256, stream);
        entrop_pass1<true><<<NBLK1, THREADS, 0, stream>>>(sr, hr, ghist, gsum);
        entrop_reduceB<<<64, THREADS, 0, stream>>>(ghist, ent);
        entrop_final<<<1, 64, 0, stream>>>(ent, gsum, out);
    }
}